// Round 1
// baseline (5725.517 us; speedup 1.0000x reference)
//
#include <hip/hip_runtime.h>
#include <hip/hip_bf16.h>

// Problem constants (match reference)
#define N_NODES  100000
#define N_EDGES  1600000
#define N_GRAPHS 2048
#define DIM      128   // IN_DIM == HIDDEN == 128

// ---------------------------------------------------------------------------
// Edge scatter: for each edge e, Acc[dst[e]][:] += V[src[e]][:]  (128 fp32)
// One edge per 32-lane group, float4 per lane.
// ---------------------------------------------------------------------------
__global__ __launch_bounds__(256)
void edge_scatter(const int* __restrict__ src, const int* __restrict__ dst,
                  const float* __restrict__ V, float* __restrict__ Acc, int E)
{
    int e = blockIdx.x * 8 + (threadIdx.x >> 5);
    int lane = threadIdx.x & 31;
    if (e >= E) return;
    int s = src[e];
    int d = dst[e];
    const float4 v = ((const float4*)V)[(size_t)s * 32 + lane];
    float* out = Acc + (size_t)d * DIM + lane * 4;
    atomicAdd(out + 0, v.x);
    atomicAdd(out + 1, v.y);
    atomicAdd(out + 2, v.z);
    atomicAdd(out + 3, v.w);
}

// Degree count (incoming edges per dst), accumulated as float (exact <= 2^24)
__global__ __launch_bounds__(256)
void deg_count(const int* __restrict__ dst, float* __restrict__ deg, int E)
{
    int e = blockIdx.x * blockDim.x + threadIdx.x;
    if (e < E) atomicAdd(&deg[dst[e]], 1.0f);
}

// In-place: deg[i] -> rsqrt(deg[i] + 1)
__global__ __launch_bounds__(256)
void make_dinv(float* __restrict__ deg, int N)
{
    int i = blockIdx.x * blockDim.x + threadIdx.x;
    if (i < N) deg[i] = rsqrtf(deg[i] + 1.0f);
}

// ---------------------------------------------------------------------------
// Register-tiled fp32 GEMM: Out[i][n] = f( sum_k Ain[i][k] * W[k][n] )
//   Ain = A (+ X if ADD_X), K = N = 128 fixed, M runtime.
//   Epilogue: +bias (if non-null), *dinv[row] (if SCALE_DINV), relu (if RELU),
//   dual store to Out2 (if DUAL). Block tile 64x128, thread tile 8x4.
// In-place Out2 == A is safe: a block reads only its own 64 rows (all K)
// before its epilogue writes those same rows.
// ---------------------------------------------------------------------------
#define BM 64
#define BK 32

template<bool ADD_X, bool RELU, bool SCALE_DINV, bool DUAL>
__global__ __launch_bounds__(256)
void gemm128(const float* __restrict__ A, const float* __restrict__ X,
             const float* __restrict__ W, const float* __restrict__ bias,
             const float* __restrict__ dinv,
             float* __restrict__ Out, float* __restrict__ Out2, int M)
{
    __shared__ float At[BK][BM + 4];   // transposed A tile; +4 keeps 16B align
    __shared__ float Bs[BK][DIM];

    const int tid  = threadIdx.x;
    const int tidx = tid & 31;     // 32 col groups * 4 cols = 128
    const int tidy = tid >> 5;     // 8 row groups * 8 rows = 64
    const int row0 = blockIdx.x * BM;

    float acc[8][4];
#pragma unroll
    for (int i = 0; i < 8; ++i)
#pragma unroll
        for (int j = 0; j < 4; ++j) acc[i][j] = 0.f;

    for (int kt = 0; kt < DIM; kt += BK) {
        // stage A tile (transposed): 64 rows x 32 k = 512 float4, 2/thread
#pragma unroll
        for (int l = 0; l < 2; ++l) {
            int f  = tid + l * 256;
            int r  = f >> 3;
            int kc = (f & 7) << 2;
            int gr = row0 + r;
            float4 v = make_float4(0.f, 0.f, 0.f, 0.f);
            if (gr < M) {
                v = *(const float4*)&A[(size_t)gr * DIM + kt + kc];
                if (ADD_X) {
                    float4 xv = *(const float4*)&X[(size_t)gr * DIM + kt + kc];
                    v.x += xv.x; v.y += xv.y; v.z += xv.z; v.w += xv.w;
                }
            }
            At[kc + 0][r] = v.x;
            At[kc + 1][r] = v.y;
            At[kc + 2][r] = v.z;
            At[kc + 3][r] = v.w;
        }
        // stage W tile: 32 rows x 128 cols = 1024 float4, 4/thread
#pragma unroll
        for (int l = 0; l < 4; ++l) {
            int f  = tid + l * 256;
            int r  = f >> 5;
            int c4 = (f & 31) << 2;
            *(float4*)&Bs[r][c4] = *(const float4*)&W[(size_t)(kt + r) * DIM + c4];
        }
        __syncthreads();

#pragma unroll
        for (int kk = 0; kk < BK; ++kk) {
            float4 b = *(const float4*)&Bs[kk][tidx << 2];
            float a[8];
#pragma unroll
            for (int i = 0; i < 8; ++i) a[i] = At[kk][tidy * 8 + i];
#pragma unroll
            for (int i = 0; i < 8; ++i) {
                acc[i][0] = fmaf(a[i], b.x, acc[i][0]);
                acc[i][1] = fmaf(a[i], b.y, acc[i][1]);
                acc[i][2] = fmaf(a[i], b.z, acc[i][2]);
                acc[i][3] = fmaf(a[i], b.w, acc[i][3]);
            }
        }
        __syncthreads();
    }

    // epilogue
    const int c0 = tidx << 2;
#pragma unroll
    for (int i = 0; i < 8; ++i) {
        int r = row0 + tidy * 8 + i;
        if (r < M) {
            float4 v = make_float4(acc[i][0], acc[i][1], acc[i][2], acc[i][3]);
            if (bias) {
                v.x += bias[c0 + 0]; v.y += bias[c0 + 1];
                v.z += bias[c0 + 2]; v.w += bias[c0 + 3];
            }
            if (SCALE_DINV) {
                float di = dinv[r];
                v.x *= di; v.y *= di; v.z *= di; v.w *= di;
            }
            if (RELU) {
                v.x = fmaxf(v.x, 0.f); v.y = fmaxf(v.y, 0.f);
                v.z = fmaxf(v.z, 0.f); v.w = fmaxf(v.w, 0.f);
            }
            *(float4*)&Out[(size_t)r * DIM + c0] = v;
            if (DUAL) *(float4*)&Out2[(size_t)r * DIM + c0] = v;
        }
    }
}

// ---------------------------------------------------------------------------
// Finalize GCN + global_add_pool. batch is sorted, so accumulate runs locally
// and flush one atomic per (run, channel) per block chunk.
//   h2[r][j] = relu(dinv[r]*Acc[r][j] + bias[j]);  g[batch[r]][j] += h2[r][j]
// 128 threads (one per channel), 64 rows per block.
// ---------------------------------------------------------------------------
#define POOL_ROWS 64
__global__ __launch_bounds__(128)
void finalize_pool(const float* __restrict__ Acc, const float* __restrict__ dinv,
                   const float* __restrict__ bias, const int* __restrict__ batch,
                   float* __restrict__ g, int N)
{
    int row0 = blockIdx.x * POOL_ROWS;
    int j = threadIdx.x;
    float bj = bias[j];
    float local = 0.f;
    int prev = -1;
    int rend = row0 + POOL_ROWS;
    if (rend > N) rend = N;
    for (int r = row0; r < rend; ++r) {
        int b = batch[r];
        if (b != prev) {
            if (prev >= 0) atomicAdd(&g[(size_t)prev * DIM + j], local);
            local = 0.f;
            prev = b;
        }
        float v = fmaf(dinv[r], Acc[(size_t)r * DIM + j], bj);
        local += fmaxf(v, 0.f);
    }
    if (prev >= 0) atomicAdd(&g[(size_t)prev * DIM + j], local);
}

// ---------------------------------------------------------------------------
// Head: out[gid] = relu(g[gid] @ lin1_w + b1) @ lin2_w + b2   (per-graph block)
// ---------------------------------------------------------------------------
__global__ __launch_bounds__(128)
void head_kernel(const float* __restrict__ g, const float* __restrict__ w1,
                 const float* __restrict__ b1, const float* __restrict__ w2,
                 const float* __restrict__ b2, float* __restrict__ out)
{
    __shared__ float gs[DIM];
    __shared__ float red[6];
    int gid = blockIdx.x;
    int t = threadIdx.x;   // 0..127

    gs[t] = g[(size_t)gid * DIM + t];
    __syncthreads();

    float acc = b1[t];
#pragma unroll
    for (int k = 0; k < DIM; ++k) acc = fmaf(gs[k], w1[k * DIM + t], acc);
    float h = fmaxf(acc, 0.f);

    float c0 = h * w2[t * 3 + 0];
    float c1 = h * w2[t * 3 + 1];
    float c2 = h * w2[t * 3 + 2];
#pragma unroll
    for (int off = 32; off >= 1; off >>= 1) {
        c0 += __shfl_down(c0, off);
        c1 += __shfl_down(c1, off);
        c2 += __shfl_down(c2, off);
    }
    int wave = t >> 6;
    if ((t & 63) == 0) {
        red[wave * 3 + 0] = c0;
        red[wave * 3 + 1] = c1;
        red[wave * 3 + 2] = c2;
    }
    __syncthreads();
    if (t == 0) {
        out[(size_t)gid * 3 + 0] = red[0] + red[3] + b2[0];
        out[(size_t)gid * 3 + 1] = red[1] + red[4] + b2[1];
        out[(size_t)gid * 3 + 2] = red[2] + red[5] + b2[2];
    }
}

// ---------------------------------------------------------------------------
extern "C" void kernel_launch(void* const* d_in, const int* in_sizes, int n_in,
                              void* d_out, int out_size, void* d_ws, size_t ws_size,
                              hipStream_t stream)
{
    const float* x       = (const float*)d_in[0];
    const int*   eidx    = (const int*)d_in[1];   // [2][E] (jax default: int32)
    const int*   batch   = (const int*)d_in[2];
    const float* gin_w1  = (const float*)d_in[3];
    const float* gin_b1  = (const float*)d_in[4];
    const float* gin_w2  = (const float*)d_in[5];
    const float* gin_b2  = (const float*)d_in[6];
    const float* gcn_w   = (const float*)d_in[7];
    const float* gcn_b   = (const float*)d_in[8];
    const float* lin1_w  = (const float*)d_in[9];
    const float* lin1_b  = (const float*)d_in[10];
    const float* lin2_w  = (const float*)d_in[11];
    const float* lin2_b  = (const float*)d_in[12];

    const int* src = eidx;             // edge_index[0]
    const int* dst = eidx + N_EDGES;   // edge_index[1]

    // workspace carve (256B aligned)
    const size_t NB = (size_t)N_NODES * DIM * sizeof(float);   // 51.2 MB
    char* base = (char*)d_ws;
    size_t off = 0;
    auto carve = [&](size_t bytes) {
        char* p = base + off;
        off = (off + bytes + 255) & ~(size_t)255;
        return p;
    };
    float* bufA = (float*)carve(NB);                       // agg -> h -> acc
    float* bufB = (float*)carve(NB);                       // h1 -> u
    float* deg  = (float*)carve(N_NODES * sizeof(float));  // deg -> dinv
    float* g    = (float*)carve((size_t)N_GRAPHS * DIM * sizeof(float));

    // zero what needs zeroing
    hipMemsetAsync(bufA, 0, NB, stream);
    hipMemsetAsync(deg, 0, N_NODES * sizeof(float), stream);
    hipMemsetAsync(g, 0, (size_t)N_GRAPHS * DIM * sizeof(float), stream);

    const int egrid = (N_EDGES + 7) / 8;
    const int ggrid = (N_NODES + BM - 1) / BM;

    // 1) GIN aggregate: bufA = segment_sum(x[src], dst)
    edge_scatter<<<egrid, 256, 0, stream>>>(src, dst, x, bufA, N_EDGES);
    // degree (for GCN) can run concurrently-ordered on same stream
    deg_count<<<(N_EDGES + 255) / 256, 256, 0, stream>>>(dst, deg, N_EDGES);
    make_dinv<<<(N_NODES + 255) / 256, 256, 0, stream>>>(deg, N_NODES);

    // 2) GIN MLP: h1 = relu((agg + x) @ w1 + b1) ; h = relu(h1 @ w2 + b2)
    gemm128<true,  true,  false, false><<<ggrid, 256, 0, stream>>>(
        bufA, x, gin_w1, gin_b1, nullptr, bufB, nullptr, N_NODES);
    gemm128<false, true,  false, false><<<ggrid, 256, 0, stream>>>(
        bufB, nullptr, gin_w2, gin_b2, nullptr, bufA, nullptr, N_NODES);

    // 3) GCN: u = dinv * (h @ gcn_w); store u to bufB (gather src) and
    //    in-place to bufA (accumulator init = self term u_i)
    gemm128<false, false, true,  true><<<ggrid, 256, 0, stream>>>(
        bufA, nullptr, gcn_w, nullptr, deg, bufB, bufA, N_NODES);

    // 4) GCN message pass: bufA[dst] += u[src]
    edge_scatter<<<egrid, 256, 0, stream>>>(src, dst, bufB, bufA, N_EDGES);

    // 5) finalize (relu(dinv*acc + b)) + global_add_pool (batch sorted)
    finalize_pool<<<(N_NODES + POOL_ROWS - 1) / POOL_ROWS, 128, 0, stream>>>(
        bufA, deg, gcn_b, batch, g, N_NODES);

    // 6) head
    head_kernel<<<N_GRAPHS, 128, 0, stream>>>(
        g, lin1_w, lin1_b, lin2_w, lin2_b, (float*)d_out);
}

// Round 2
// 729.594 us; speedup vs baseline: 7.8475x; 7.8475x over previous
//
#include <hip/hip_runtime.h>
#include <hip/hip_bf16.h>

// Problem constants (match reference)
#define N_NODES  100000
#define N_EDGES  1600000
#define N_GRAPHS 2048
#define DIM      128   // IN_DIM == HIDDEN == 128

// ===========================================================================
// CSR construction: count -> 3-phase exclusive scan -> cursor fill
// ===========================================================================
__global__ __launch_bounds__(256)
void cnt_kernel(const int* __restrict__ dst, int* __restrict__ cnt, int E)
{
    int e = blockIdx.x * blockDim.x + threadIdx.x;
    if (e < E) atomicAdd(&cnt[dst[e]], 1);
}

#define SCAN_T     256
#define SCAN_E     4
#define SCAN_CHUNK 1024   // SCAN_T * SCAN_E
#define SCAN_NBLK  ((N_NODES + SCAN_CHUNK - 1) / SCAN_CHUNK)   // 98

// Phase 1: per-block local exclusive scan of cnt -> rp, block totals -> bsum
__global__ __launch_bounds__(SCAN_T)
void scan1(const int* __restrict__ cnt, int* __restrict__ rp,
           int* __restrict__ bsum, int N)
{
    __shared__ int sh[SCAN_T];
    int b = blockIdx.x, t = threadIdx.x;
    int base = b * SCAN_CHUNK + t * SCAN_E;
    int v[SCAN_E];
    int s = 0;
#pragma unroll
    for (int i = 0; i < SCAN_E; ++i) {
        int idx = base + i;
        v[i] = (idx < N) ? cnt[idx] : 0;
        s += v[i];
    }
    sh[t] = s;
    __syncthreads();
    // Hillis-Steele inclusive scan over thread sums
    for (int off = 1; off < SCAN_T; off <<= 1) {
        int add = (t >= off) ? sh[t - off] : 0;
        __syncthreads();
        sh[t] += add;
        __syncthreads();
    }
    int excl = sh[t] - s;
    if (t == SCAN_T - 1) bsum[b] = sh[t];
    int run = excl;
#pragma unroll
    for (int i = 0; i < SCAN_E; ++i) {
        int idx = base + i;
        if (idx < N) rp[idx] = run;
        run += v[i];
    }
}

// Phase 2: single-block exclusive scan of block sums (SCAN_NBLK <= 128)
__global__ __launch_bounds__(128)
void scan2(int* __restrict__ bsum, int nb)
{
    __shared__ int sh[128];
    int t = threadIdx.x;
    int v = (t < nb) ? bsum[t] : 0;
    sh[t] = v;
    __syncthreads();
    for (int off = 1; off < 128; off <<= 1) {
        int add = (t >= off) ? sh[t - off] : 0;
        __syncthreads();
        sh[t] += add;
        __syncthreads();
    }
    if (t < nb) bsum[t] = sh[t] - v;   // exclusive
}

// Phase 3: add block offsets; emit row_ptr and cursor copies; rp[N] = E
__global__ __launch_bounds__(256)
void scan3(int* __restrict__ rp, int* __restrict__ cursor,
           const int* __restrict__ bsum, int N, int E)
{
    int i = blockIdx.x * blockDim.x + threadIdx.x;
    if (i < N) {
        int v = rp[i] + bsum[i / SCAN_CHUNK];
        rp[i] = v;
        cursor[i] = v;
    }
    if (i == N) rp[N] = E;
}

__global__ __launch_bounds__(256)
void csr_fill(const int* __restrict__ src, const int* __restrict__ dst,
              int* __restrict__ cursor, int* __restrict__ csr, int E)
{
    int e = blockIdx.x * blockDim.x + threadIdx.x;
    if (e < E) {
        int pos = atomicAdd(&cursor[dst[e]], 1);
        csr[pos] = src[e];
    }
}

// In-place reinterpret: int count -> float rsqrt(count + 1)
__global__ __launch_bounds__(256)
void make_dinv(int* __restrict__ cnt, int N)
{
    int i = blockIdx.x * blockDim.x + threadIdx.x;
    if (i < N) {
        float d = (float)cnt[i] + 1.0f;
        ((float*)cnt)[i] = rsqrtf(d);
    }
}

// ===========================================================================
// CSR gather: Out[i] = V[i] + sum_{e in [rp[i],rp[i+1])} V[csr[e]]
// One node per 32-lane group, float4 per lane. No atomics.
// ===========================================================================
__global__ __launch_bounds__(256)
void csr_gather(const int* __restrict__ rp, const int* __restrict__ csr,
                const float* __restrict__ V, float* __restrict__ Out, int N)
{
    int node = blockIdx.x * 8 + (threadIdx.x >> 5);
    int lane = threadIdx.x & 31;
    if (node >= N) return;
    int beg = rp[node];
    int end = rp[node + 1];
    const float4* V4 = (const float4*)V;
    float4 acc = V4[(size_t)node * 32 + lane];   // self term
    for (int e = beg; e < end; ++e) {
        int s = csr[e];
        float4 v = V4[(size_t)s * 32 + lane];
        acc.x += v.x; acc.y += v.y; acc.z += v.z; acc.w += v.w;
    }
    ((float4*)Out)[(size_t)node * 32 + lane] = acc;
}

// ===========================================================================
// Register-tiled fp32 GEMM: Out[i][n] = f( sum_k A[i][k] * W[k][n] )
//   K = N = 128 fixed, M runtime. Epilogue: +bias (if non-null),
//   *dinv[row] (if SCALE_DINV), relu (if RELU). Block tile 64x128,
//   thread tile 8x4.
// ===========================================================================
#define BM 64
#define BK 32

template<bool RELU, bool SCALE_DINV>
__global__ __launch_bounds__(256)
void gemm128(const float* __restrict__ A, const float* __restrict__ W,
             const float* __restrict__ bias, const float* __restrict__ dinv,
             float* __restrict__ Out, int M)
{
    __shared__ float At[BK][BM + 4];
    __shared__ float Bs[BK][DIM];

    const int tid  = threadIdx.x;
    const int tidx = tid & 31;
    const int tidy = tid >> 5;
    const int row0 = blockIdx.x * BM;

    float acc[8][4];
#pragma unroll
    for (int i = 0; i < 8; ++i)
#pragma unroll
        for (int j = 0; j < 4; ++j) acc[i][j] = 0.f;

    for (int kt = 0; kt < DIM; kt += BK) {
#pragma unroll
        for (int l = 0; l < 2; ++l) {
            int f  = tid + l * 256;
            int r  = f >> 3;
            int kc = (f & 7) << 2;
            int gr = row0 + r;
            float4 v = make_float4(0.f, 0.f, 0.f, 0.f);
            if (gr < M) v = *(const float4*)&A[(size_t)gr * DIM + kt + kc];
            At[kc + 0][r] = v.x;
            At[kc + 1][r] = v.y;
            At[kc + 2][r] = v.z;
            At[kc + 3][r] = v.w;
        }
#pragma unroll
        for (int l = 0; l < 4; ++l) {
            int f  = tid + l * 256;
            int r  = f >> 5;
            int c4 = (f & 31) << 2;
            *(float4*)&Bs[r][c4] = *(const float4*)&W[(size_t)(kt + r) * DIM + c4];
        }
        __syncthreads();

#pragma unroll
        for (int kk = 0; kk < BK; ++kk) {
            float4 b = *(const float4*)&Bs[kk][tidx << 2];
            float a[8];
#pragma unroll
            for (int i = 0; i < 8; ++i) a[i] = At[kk][tidy * 8 + i];
#pragma unroll
            for (int i = 0; i < 8; ++i) {
                acc[i][0] = fmaf(a[i], b.x, acc[i][0]);
                acc[i][1] = fmaf(a[i], b.y, acc[i][1]);
                acc[i][2] = fmaf(a[i], b.z, acc[i][2]);
                acc[i][3] = fmaf(a[i], b.w, acc[i][3]);
            }
        }
        __syncthreads();
    }

    const int c0 = tidx << 2;
#pragma unroll
    for (int i = 0; i < 8; ++i) {
        int r = row0 + tidy * 8 + i;
        if (r < M) {
            float4 v = make_float4(acc[i][0], acc[i][1], acc[i][2], acc[i][3]);
            if (bias) {
                v.x += bias[c0 + 0]; v.y += bias[c0 + 1];
                v.z += bias[c0 + 2]; v.w += bias[c0 + 3];
            }
            if (SCALE_DINV) {
                float di = dinv[r];
                v.x *= di; v.y *= di; v.z *= di; v.w *= di;
            }
            if (RELU) {
                v.x = fmaxf(v.x, 0.f); v.y = fmaxf(v.y, 0.f);
                v.z = fmaxf(v.z, 0.f); v.w = fmaxf(v.w, 0.f);
            }
            *(float4*)&Out[(size_t)r * DIM + c0] = v;
        }
    }
}

// ===========================================================================
// Finalize GCN + global_add_pool (batch sorted -> run-length local sums)
// ===========================================================================
#define POOL_ROWS 64
__global__ __launch_bounds__(128)
void finalize_pool(const float* __restrict__ Acc, const float* __restrict__ dinv,
                   const float* __restrict__ bias, const int* __restrict__ batch,
                   float* __restrict__ g, int N)
{
    int row0 = blockIdx.x * POOL_ROWS;
    int j = threadIdx.x;
    float bj = bias[j];
    float local = 0.f;
    int prev = -1;
    int rend = row0 + POOL_ROWS;
    if (rend > N) rend = N;
    for (int r = row0; r < rend; ++r) {
        int b = batch[r];
        if (b != prev) {
            if (prev >= 0) atomicAdd(&g[(size_t)prev * DIM + j], local);
            local = 0.f;
            prev = b;
        }
        float v = fmaf(dinv[r], Acc[(size_t)r * DIM + j], bj);
        local += fmaxf(v, 0.f);
    }
    if (prev >= 0) atomicAdd(&g[(size_t)prev * DIM + j], local);
}

// ===========================================================================
// Head: out[gid] = relu(g[gid] @ lin1_w + b1) @ lin2_w + b2
// ===========================================================================
__global__ __launch_bounds__(128)
void head_kernel(const float* __restrict__ g, const float* __restrict__ w1,
                 const float* __restrict__ b1, const float* __restrict__ w2,
                 const float* __restrict__ b2, float* __restrict__ out)
{
    __shared__ float gs[DIM];
    __shared__ float red[6];
    int gid = blockIdx.x;
    int t = threadIdx.x;

    gs[t] = g[(size_t)gid * DIM + t];
    __syncthreads();

    float acc = b1[t];
#pragma unroll
    for (int k = 0; k < DIM; ++k) acc = fmaf(gs[k], w1[k * DIM + t], acc);
    float h = fmaxf(acc, 0.f);

    float c0 = h * w2[t * 3 + 0];
    float c1 = h * w2[t * 3 + 1];
    float c2 = h * w2[t * 3 + 2];
#pragma unroll
    for (int off = 32; off >= 1; off >>= 1) {
        c0 += __shfl_down(c0, off);
        c1 += __shfl_down(c1, off);
        c2 += __shfl_down(c2, off);
    }
    int wave = t >> 6;
    if ((t & 63) == 0) {
        red[wave * 3 + 0] = c0;
        red[wave * 3 + 1] = c1;
        red[wave * 3 + 2] = c2;
    }
    __syncthreads();
    if (t == 0) {
        out[(size_t)gid * 3 + 0] = red[0] + red[3] + b2[0];
        out[(size_t)gid * 3 + 1] = red[1] + red[4] + b2[1];
        out[(size_t)gid * 3 + 2] = red[2] + red[5] + b2[2];
    }
}

// ===========================================================================
extern "C" void kernel_launch(void* const* d_in, const int* in_sizes, int n_in,
                              void* d_out, int out_size, void* d_ws, size_t ws_size,
                              hipStream_t stream)
{
    const float* x       = (const float*)d_in[0];
    const int*   eidx    = (const int*)d_in[1];
    const int*   batch   = (const int*)d_in[2];
    const float* gin_w1  = (const float*)d_in[3];
    const float* gin_b1  = (const float*)d_in[4];
    const float* gin_w2  = (const float*)d_in[5];
    const float* gin_b2  = (const float*)d_in[6];
    const float* gcn_w   = (const float*)d_in[7];
    const float* gcn_b   = (const float*)d_in[8];
    const float* lin1_w  = (const float*)d_in[9];
    const float* lin1_b  = (const float*)d_in[10];
    const float* lin2_w  = (const float*)d_in[11];
    const float* lin2_b  = (const float*)d_in[12];

    const int* src = eidx;
    const int* dst = eidx + N_EDGES;

    // workspace carve (256B aligned)
    const size_t NB = (size_t)N_NODES * DIM * sizeof(float);   // 51.2 MB
    char* base = (char*)d_ws;
    size_t off = 0;
    auto carve = [&](size_t bytes) {
        char* p = base + off;
        off = (off + bytes + 255) & ~(size_t)255;
        return p;
    };
    float* bufA   = (float*)carve(NB);
    float* bufB   = (float*)carve(NB);
    int*   cnt    = (int*)  carve(N_NODES * sizeof(int));      // cnt -> dinv
    int*   rp     = (int*)  carve((N_NODES + 1) * sizeof(int));
    int*   cursor = (int*)  carve(N_NODES * sizeof(int));
    int*   csr    = (int*)  carve((size_t)N_EDGES * sizeof(int));
    int*   bsum   = (int*)  carve(SCAN_NBLK * sizeof(int));
    float* g      = (float*)carve((size_t)N_GRAPHS * DIM * sizeof(float));
    float* dinv   = (float*)cnt;   // in-place conversion after CSR build

    hipMemsetAsync(cnt, 0, N_NODES * sizeof(int), stream);
    hipMemsetAsync(g, 0, (size_t)N_GRAPHS * DIM * sizeof(float), stream);

    const int egrid = (N_EDGES + 255) / 256;
    const int ngrid = (N_NODES + 7) / 8;
    const int ggrid = (N_NODES + BM - 1) / BM;

    // ---- CSR build ----
    cnt_kernel<<<egrid, 256, 0, stream>>>(dst, cnt, N_EDGES);
    scan1<<<SCAN_NBLK, SCAN_T, 0, stream>>>(cnt, rp, bsum, N_NODES);
    scan2<<<1, 128, 0, stream>>>(bsum, SCAN_NBLK);
    scan3<<<(N_NODES + 256) / 256, 256, 0, stream>>>(rp, cursor, bsum, N_NODES, N_EDGES);
    csr_fill<<<egrid, 256, 0, stream>>>(src, dst, cursor, csr, N_EDGES);
    make_dinv<<<(N_NODES + 255) / 256, 256, 0, stream>>>(cnt, N_NODES);

    // ---- GIN: bufA = x + segment_sum(x[src], dst) ----
    csr_gather<<<ngrid, 256, 0, stream>>>(rp, csr, x, bufA, N_NODES);

    // ---- GIN MLP ----
    gemm128<true,  false><<<ggrid, 256, 0, stream>>>(bufA, gin_w1, gin_b1, nullptr, bufB, N_NODES);
    gemm128<true,  false><<<ggrid, 256, 0, stream>>>(bufB, gin_w2, gin_b2, nullptr, bufA, N_NODES);

    // ---- GCN: u = dinv * (h @ gcn_w) -> bufB ----
    gemm128<false, true><<<ggrid, 256, 0, stream>>>(bufA, gcn_w, nullptr, dinv, bufB, N_NODES);

    // ---- GCN message pass: bufA[i] = u[i] + sum u[csr] ----
    csr_gather<<<ngrid, 256, 0, stream>>>(rp, csr, bufB, bufA, N_NODES);

    // ---- finalize + pool ----
    finalize_pool<<<(N_NODES + POOL_ROWS - 1) / POOL_ROWS, 128, 0, stream>>>(
        bufA, dinv, gcn_b, batch, g, N_NODES);

    // ---- head ----
    head_kernel<<<N_GRAPHS, 128, 0, stream>>>(
        g, lin1_w, lin1_b, lin2_w, lin2_b, (float*)d_out);
}